// Round 1
// 613.613 us; speedup vs baseline: 1.0432x; 1.0432x over previous
//
#include <hip/hip_runtime.h>

typedef unsigned short u16;
typedef unsigned int u32;
using f32x4 = __attribute__((ext_vector_type(4))) float;
using bf16x8 = __attribute__((ext_vector_type(8))) __bf16;

constexpr int Bc = 4, Tc = 2048, Dc = 2048, Hc = 16, Gc = 4, Kc = 128;
constexpr float EPSc = 1e-6f;

__device__ __forceinline__ u16 f2bf(float f) {
    u32 u = __float_as_uint(f);
    u = (u + 0x7fffu + ((u >> 16) & 1u)) >> 16;
    return (u16)u;
}
__device__ __forceinline__ float bf2f(u16 h) {
    return __uint_as_float(((u32)h) << 16);
}

// async global->LDS, 16B per lane; LDS dest must be wave-uniform base + lane*16
__device__ __forceinline__ void async_ld16(void* lds, const void* g) {
    __builtin_amdgcn_global_load_lds(
        (const __attribute__((address_space(1))) unsigned int*)g,
        (__attribute__((address_space(3))) unsigned int*)lds, 16, 0, 0);
}

// raw barrier: waits own LDS ops, does NOT drain vmcnt (prefetch stays in flight)
__device__ __forceinline__ void sync_lgkm() {
    asm volatile("s_waitcnt lgkmcnt(0)" ::: "memory");
    __builtin_amdgcn_s_barrier();
    asm volatile("" ::: "memory");
}

__device__ __forceinline__ u32 cvt_pk_bf16(float lo, float hi) {
    u32 r;
    asm("v_cvt_pk_bf16_f32 %0, %1, %2" : "=v"(r) : "v"(lo), "v"(hi));
    return r;
}

// ---------------- fp32 -> bf16 convert ----------------
__global__ __launch_bounds__(256) void cvt_f2bf(const float* __restrict__ in,
                                                u16* __restrict__ out, int n) {
    int i = (blockIdx.x * 256 + threadIdx.x) * 4;
    if (i >= n) return;
    float4 f = *(const float4*)(in + i);
    u16 r[4] = { f2bf(f.x), f2bf(f.y), f2bf(f.z), f2bf(f.w) };
    *(uint2*)(out + i) = *(uint2*)r;
}

// ------- transpose+convert: in (rows x cols) f32 -> out (cols x rows) bf16 -------
__global__ __launch_bounds__(256) void transpose_f2bf(const float* __restrict__ in,
                                                      u16* __restrict__ out,
                                                      int rows, int cols) {
    __shared__ float tile[32][33];
    int tx = threadIdx.x & 31, ty = threadIdx.x >> 5;
    int c0 = blockIdx.x * 32, r0 = blockIdx.y * 32;
#pragma unroll
    for (int j = 0; j < 4; j++)
        tile[ty + j * 8][tx] = in[(size_t)(r0 + ty + j * 8) * cols + c0 + tx];
    __syncthreads();
#pragma unroll
    for (int j = 0; j < 4; j++)
        out[(size_t)(c0 + ty + j * 8) * rows + r0 + tx] = f2bf(tile[tx][ty + j * 8]);
}

// ---------------- positions from (sorted) segment ids ----------------
__global__ void pos_kernel(const int* __restrict__ seg, int* __restrict__ pos) {
    int idx = blockIdx.x * 256 + threadIdx.x;
    if (idx >= Bc * Tc) return;
    int b = idx / Tc, t = idx - b * Tc;
    const int* s = seg + b * Tc;
    int v = s[t];
    int lo = 0, hi = t;
    while (lo < hi) { int mid = (lo + hi) >> 1; if (s[mid] < v) lo = mid + 1; else hi = mid; }
    pos[idx] = t - lo;   // t - seg_start
}

// ---------------- bf16 GEMM (m97 structure): C(MxN) = A(MxKd) * Bt(NxKd)^T ----------------
#define GBM 128
#define GBN 128
#define GBK 32

__global__ __launch_bounds__(256) void gemm_bt(const u16* __restrict__ A,
                                               const u16* __restrict__ Bt,
                                               float* __restrict__ Cf, u16* __restrict__ Cb,
                                               int M, int N, int Kd) {
    __shared__ __align__(16) u16 lA[GBM * GBK];   // unpadded: required by global_load_lds lane order
    __shared__ __align__(16) u16 lB[GBN * GBK];
    const int tid = threadIdx.x;
    const int m0 = blockIdx.y * GBM, n0 = blockIdx.x * GBN;
    const int wave = tid >> 6, lane = tid & 63;
    const int l16 = lane & 15, quad = lane >> 4;
    const int wm = (wave & 1) * 64, wn = (wave >> 1) * 64;

    const int c0 = tid, c1 = tid + 256;
    const u16* gA0 = A + (size_t)(m0 + (c0 >> 2)) * Kd + (c0 & 3) * 8;
    const u16* gA1 = A + (size_t)(m0 + (c1 >> 2)) * Kd + (c1 & 3) * 8;
    const u16* gB0 = Bt + (size_t)(n0 + (c0 >> 2)) * Kd + (c0 & 3) * 8;
    const u16* gB1 = Bt + (size_t)(n0 + (c1 >> 2)) * Kd + (c1 & 3) * 8;
    u16* sA0 = &lA[c0 * 8];
    u16* sA1 = &lA[c1 * 8];
    u16* sB0 = &lB[c0 * 8];
    u16* sB1 = &lB[c1 * 8];

    const f32x4 fz = {0.f, 0.f, 0.f, 0.f};
    f32x4 acc[4][4];
#pragma unroll
    for (int i = 0; i < 4; i++)
#pragma unroll
        for (int j = 0; j < 4; j++) acc[i][j] = fz;

    for (int k0 = 0; k0 < Kd; k0 += GBK) {
        __syncthreads();
        async_ld16(sA0, gA0 + k0);
        async_ld16(sA1, gA1 + k0);
        async_ld16(sB0, gB0 + k0);
        async_ld16(sB1, gB1 + k0);
        __syncthreads();
        bf16x8 af[4], bg[4];
#pragma unroll
        for (int i = 0; i < 4; i++) {
            af[i] = *(const bf16x8*)&lA[(wm + i * 16 + l16) * GBK + quad * 8];
            bg[i] = *(const bf16x8*)&lB[(wn + i * 16 + l16) * GBK + quad * 8];
        }
#pragma unroll
        for (int mi = 0; mi < 4; mi++)
#pragma unroll
            for (int ni = 0; ni < 4; ni++)
                acc[mi][ni] = __builtin_amdgcn_mfma_f32_16x16x32_bf16(af[mi], bg[ni], acc[mi][ni], 0, 0, 0);
    }

#pragma unroll
    for (int mi = 0; mi < 4; mi++)
#pragma unroll
        for (int ni = 0; ni < 4; ni++)
#pragma unroll
            for (int r = 0; r < 4; r++) {
                int row = m0 + wm + mi * 16 + quad * 4 + r;   // C/D: row=quad*4+reg
                int col = n0 + wn + ni * 16 + l16;            //      col=lane&15
                float v = acc[mi][ni][r];
                if (Cf) Cf[(size_t)row * N + col] = v;
                else    Cb[(size_t)row * N + col] = f2bf(v);
            }
}

// ------- merged QKV GEMM: N=3072 over [wqT;wkT;wvT]; Q->qb, K->kb, V->Vt[b][g][d][t] -------
__global__ __launch_bounds__(256) void gemm_qkv(const u16* __restrict__ A,
                                                const u16* __restrict__ Bt,
                                                u16* __restrict__ qb, u16* __restrict__ kb,
                                                u16* __restrict__ vtb, int M, int Kd) {
    __shared__ __align__(16) u16 lA[GBM * GBK];
    __shared__ __align__(16) u16 lB[GBN * GBK];
    const int tid = threadIdx.x;
    const int m0 = blockIdx.y * GBM, n0 = blockIdx.x * GBN;
    const int wave = tid >> 6, lane = tid & 63;
    const int l16 = lane & 15, quad = lane >> 4;
    const int wm = (wave & 1) * 64, wn = (wave >> 1) * 64;

    const int c0 = tid, c1 = tid + 256;
    const u16* gA0 = A + (size_t)(m0 + (c0 >> 2)) * Kd + (c0 & 3) * 8;
    const u16* gA1 = A + (size_t)(m0 + (c1 >> 2)) * Kd + (c1 & 3) * 8;
    const u16* gB0 = Bt + (size_t)(n0 + (c0 >> 2)) * Kd + (c0 & 3) * 8;
    const u16* gB1 = Bt + (size_t)(n0 + (c1 >> 2)) * Kd + (c1 & 3) * 8;
    u16* sA0 = &lA[c0 * 8];
    u16* sA1 = &lA[c1 * 8];
    u16* sB0 = &lB[c0 * 8];
    u16* sB1 = &lB[c1 * 8];

    const f32x4 fz = {0.f, 0.f, 0.f, 0.f};
    f32x4 acc[4][4];
#pragma unroll
    for (int i = 0; i < 4; i++)
#pragma unroll
        for (int j = 0; j < 4; j++) acc[i][j] = fz;

    for (int k0 = 0; k0 < Kd; k0 += GBK) {
        __syncthreads();
        async_ld16(sA0, gA0 + k0);
        async_ld16(sA1, gA1 + k0);
        async_ld16(sB0, gB0 + k0);
        async_ld16(sB1, gB1 + k0);
        __syncthreads();
        bf16x8 af[4], bg[4];
#pragma unroll
        for (int i = 0; i < 4; i++) {
            af[i] = *(const bf16x8*)&lA[(wm + i * 16 + l16) * GBK + quad * 8];
            bg[i] = *(const bf16x8*)&lB[(wn + i * 16 + l16) * GBK + quad * 8];
        }
#pragma unroll
        for (int mi = 0; mi < 4; mi++)
#pragma unroll
            for (int ni = 0; ni < 4; ni++)
                acc[mi][ni] = __builtin_amdgcn_mfma_f32_16x16x32_bf16(af[mi], bg[ni], acc[mi][ni], 0, 0, 0);
    }

    const int nbase = n0 + wn;   // 64-aligned; regions split at 2048 / 2560 (both 64-aligned)
    if (nbase < 2048) {
        // Q: qb[(b,t)][(h,d)] = [M][2048]
#pragma unroll
        for (int mi = 0; mi < 4; mi++)
#pragma unroll
            for (int ni = 0; ni < 4; ni++)
#pragma unroll
                for (int r = 0; r < 4; r++) {
                    int row = m0 + wm + mi * 16 + quad * 4 + r;
                    int col = nbase + ni * 16 + l16;
                    qb[(size_t)row * 2048 + col] = f2bf(acc[mi][ni][r]);
                }
    } else if (nbase < 2560) {
        // K: kb[(b,t)][(g,d)] = [M][512]
#pragma unroll
        for (int mi = 0; mi < 4; mi++)
#pragma unroll
            for (int ni = 0; ni < 4; ni++)
#pragma unroll
                for (int r = 0; r < 4; r++) {
                    int row = m0 + wm + mi * 16 + quad * 4 + r;
                    int col = nbase + ni * 16 + l16 - 2048;
                    kb[(size_t)row * 512 + col] = f2bf(acc[mi][ni][r]);
                }
    } else {
        // V: transposed Vt[b][g][d][t]; 4 consecutive t per lane -> 8B store
#pragma unroll
        for (int mi = 0; mi < 4; mi++)
#pragma unroll
            for (int ni = 0; ni < 4; ni++) {
                int nv = nbase + ni * 16 + l16 - 2560;
                int g = nv >> 7, d = nv & 127;
                int m = m0 + wm + mi * 16 + quad * 4;
                int b = m >> 11, t = m & 2047;
                u16 r4[4];
#pragma unroll
                for (int r = 0; r < 4; r++) r4[r] = f2bf(acc[mi][ni][r]);
                *(uint2*)&vtb[(((size_t)b * Gc + g) * Kc + d) * Tc + t] = *(uint2*)r4;
            }
    }
}

// ---------------- fused RMSNorm + RoPE (+ optional smul fold), in place ----------------
__global__ __launch_bounds__(256) void rms_rope(u16* __restrict__ X,
                                                const float* __restrict__ sc,
                                                const int* __restrict__ pos, int NH,
                                                float smul) {
    int row = blockIdx.x * 4 + (threadIdx.x >> 6);   // one wave per (b,t,head) row
    int lane = threadIdx.x & 63;
    int bt = row / NH;
    u16* xp = X + (size_t)row * Kc;
    float x1 = bf2f(xp[lane]), x2 = bf2f(xp[lane + 64]);   // rope pairs (j, j+64)
    float ss = x1 * x1 + x2 * x2;
#pragma unroll
    for (int m = 1; m < 64; m <<= 1) ss += __shfl_xor(ss, m, 64);
    float rn = rsqrtf(ss * (1.f / 128.f) + EPSc) * smul;   // fold attn scale into q
    float y1 = x1 * rn * sc[lane];
    float y2 = x2 * rn * sc[lane + 64];
    float inv_freq = expf(-logf(10000.f) * ((float)(2 * lane) * (1.f / 128.f)));
    float ang = (float)pos[bt] * inv_freq;
    float sv, cv;
    sincosf(ang, &sv, &cv);
    xp[lane]      = f2bf(y1 * cv - y2 * sv);
    xp[lane + 64] = f2bf(y2 * cv + y1 * sv);
}

// ---------------- flash attention: swapped-QK^T, in-register softmax ----------------
// S^T = mfma(K_frag, Q_frag): lane's col t = l16 -> m/l/alpha are per-lane scalars.
// P^T B-fragment for PV built via cvt_pk_bf16 + 16x ds_bpermute (no lP LDS round trip).
// Raw s_barrier (no vmcnt drain): next-tile prefetch loads stay in flight across
// the barrier and drain at the next iteration's ds_write (full compute overlap).
#define KSTR 136   // 128+8: stride 68 dwords == 4 mod 32 -> conflict-minimal frag reads
#define VSTR 72    // 64+8:  stride 36 dwords == 4 mod 32

__global__ __launch_bounds__(256, 4) void flash_attn(const u16* __restrict__ Qb,
                                                     const u16* __restrict__ Kb,
                                                     const u16* __restrict__ Vt,
                                                     const int* __restrict__ seg,
                                                     const int* __restrict__ pos,
                                                     u16* __restrict__ Ob) {
    __shared__ __align__(16) u16 lK[64 * KSTR];
    __shared__ __align__(16) u16 lVt[128 * VSTR];   // V transposed: [d][s]
    __shared__ int lSeg[64];                        // seg id per s of current tile

    const int b = blockIdx.z, h = blockIdx.y, g = h >> 2;        // g = h / R, R=4
    const int q0 = ((int)gridDim.x - 1 - (int)blockIdx.x) * 64;  // heavy tiles first
    const int tid = threadIdx.x;
    const int wave = tid >> 6, lane = tid & 63;
    const int l16 = lane & 15, quad = lane >> 4;

    // Q fragments in registers (already scaled by K^-0.5 in rms_rope).
    // Used as the B-operand of the swapped QK^T (same per-lane layout as A).
    bf16x8 qf[4];
#pragma unroll
    for (int kk = 0; kk < 4; kk++)
        qf[kk] = *(const bf16x8*)&Qb[((size_t)(b * Tc + q0 + wave * 16 + l16) * Hc + h) * Kc + kk * 32 + quad * 8];

    const int tg1 = q0 + wave * 16 + l16;          // this lane's q row (t)
    const int sgt1 = seg[b * Tc + tg1];
    const bool segQuni = (seg[b * Tc + q0] == seg[b * Tc + q0 + 63]);

    float m_i = -1e30f, l_i = 0.f;                 // per-lane scalars (t = l16 col)
    const f32x4 fz = {0.f, 0.f, 0.f, 0.f};
    f32x4 oc[8];   // O^T C-tiles: row d = ni*16+quad*4+r, col t = wave*16+l16
#pragma unroll
    for (int i = 0; i < 8; i++) oc[i] = fz;

    const int seg_start_exact = q0 - pos[b * Tc + q0];   // first index of q0's segment
    const int s_begin = (seg_start_exact >> 6) << 6;     // tile-aligned (may include prev segment!)

    // bpermute source addrs for the P^T quad-redistribution:
    //   word m' of bp at lane (l16,q) <- W[2kk+(q>>1)][m'&1] from lane l16+16*((q&1)*2+(m'>>1))
    const int addrA = (l16 + ((quad & 1) << 5)) << 2;   // m' = 0,1
    const int addrB = addrA + 64;                       // m' = 2,3
    const bool hiq = quad >= 2;

    // prefetch first K/V tile + seg row into registers
    uint4 kpre[4], vpre[4];
#pragma unroll
    for (int it = 0; it < 4; it++) {
        int c = tid + it * 256;
        kpre[it] = *(const uint4*)&Kb[((size_t)(b * Tc + s_begin + (c >> 4)) * Gc + g) * Kc + (c & 15) * 8];
        vpre[it] = *(const uint4*)&Vt[(((size_t)b * Gc + g) * Kc + (c >> 3)) * Tc + s_begin + (c & 7) * 8];
    }
    int segpre = (tid < 64) ? seg[b * Tc + s_begin + tid] : 0;

    for (int s0 = s_begin; s0 <= q0; s0 += 64) {
        sync_lgkm();   // all waves' LDS reads of prior tile done (no vmcnt drain)
        // stage K tile (64 x 128) and Vt tile (128 x 64) from prefetch regs
        // (compiler waits vmcnt for kpre/vpre deps here -> latency was hidden under compute)
#pragma unroll
        for (int it = 0; it < 4; it++) {
            int c = tid + it * 256;
            *(uint4*)&lK[(c >> 4) * KSTR + (c & 15) * 8] = kpre[it];
        }
#pragma unroll
        for (int it = 0; it < 4; it++) {
            int c = tid + it * 256;
            *(uint4*)&lVt[(c >> 3) * VSTR + (c & 7) * 8] = vpre[it];
        }
        if (tid < 64) lSeg[tid] = segpre;
        // prefetch next tile: stays in flight across the barrier below
        if (s0 + 64 <= q0) {
#pragma unroll
            for (int it = 0; it < 4; it++) {
                int c = tid + it * 256;
                kpre[it] = *(const uint4*)&Kb[((size_t)(b * Tc + s0 + 64 + (c >> 4)) * Gc + g) * Kc + (c & 15) * 8];
                vpre[it] = *(const uint4*)&Vt[(((size_t)b * Gc + g) * Kc + (c >> 3)) * Tc + s0 + 64 + (c & 7) * 8];
            }
            if (tid < 64) segpre = seg[b * Tc + s0 + 64 + tid];
        }
        sync_lgkm();   // staging visible; vmem prefetch NOT drained

        // S^T = K Q^T : row s = mi*16+quad*4+r, col t = l16
        f32x4 sacc[4];
#pragma unroll
        for (int mi = 0; mi < 4; mi++) sacc[mi] = fz;
        __builtin_amdgcn_s_setprio(1);
#pragma unroll
        for (int kk = 0; kk < 4; kk++) {
#pragma unroll
            for (int mi = 0; mi < 4; mi++) {
                bf16x8 bk = *(const bf16x8*)&lK[(mi * 16 + l16) * KSTR + kk * 32 + quad * 8];
                sacc[mi] = __builtin_amdgcn_mfma_f32_16x16x32_bf16(bk, qf[kk], sacc[mi], 0, 0, 0);
            }
        }
        __builtin_amdgcn_s_setprio(0);

        // mask + row max (row = fixed t per lane; s spans regs + quads)
        const bool fast = segQuni && (s0 >= seg_start_exact) && (s0 + 64 <= q0);
        float rmax = -1e30f;
        if (fast) {
#pragma unroll
            for (int mi = 0; mi < 4; mi++)
#pragma unroll
                for (int r = 0; r < 4; r++) rmax = fmaxf(rmax, sacc[mi][r]);
        } else {
#pragma unroll
            for (int mi = 0; mi < 4; mi++) {
                int sl = mi * 16 + quad * 4;
#pragma unroll
                for (int r = 0; r < 4; r++) {
                    bool ok = (s0 + sl + r <= tg1) && (lSeg[sl + r] == sgt1);
                    float x = ok ? sacc[mi][r] : -1e30f;
                    sacc[mi][r] = x;
                    rmax = fmaxf(rmax, x);
                }
            }
        }
        rmax = fmaxf(rmax, __shfl_xor(rmax, 16, 64));
        rmax = fmaxf(rmax, __shfl_xor(rmax, 32, 64));

        float mnew = fmaxf(m_i, rmax);
        float alpha = __expf(m_i - mnew);
        m_i = mnew;

        // P = exp(S - m); pack to bf16 pairs in-register
        float psum = 0.f;
        u32 W[4][2];
#pragma unroll
        for (int mi = 0; mi < 4; mi++) {
            float p[4];
#pragma unroll
            for (int r = 0; r < 4; r++) {
                float x = sacc[mi][r];
                p[r] = (x > -1e29f) ? __expf(x - m_i) : 0.f;
                psum += p[r];
            }
            W[mi][0] = cvt_pk_bf16(p[0], p[1]);
            W[mi][1] = cvt_pk_bf16(p[2], p[3]);
        }
        psum += __shfl_xor(psum, 16, 64);
        psum += __shfl_xor(psum, 32, 64);
        l_i = l_i * alpha + psum;

        // rescale O^T (col t = l16 matches per-lane alpha)
#pragma unroll
        for (int ni = 0; ni < 8; ni++)
#pragma unroll
            for (int r = 0; r < 4; r++) oc[ni][r] *= alpha;

        // O^T += V^T P^T ; P^T B-frag built via quad redistribution (16 bpermute)
#pragma unroll
        for (int kk = 0; kk < 2; kk++) {
            u32 w0a = (u32)__builtin_amdgcn_ds_bpermute(addrA, (int)W[2 * kk][0]);
            u32 w0b = (u32)__builtin_amdgcn_ds_bpermute(addrA, (int)W[2 * kk + 1][0]);
            u32 w1a = (u32)__builtin_amdgcn_ds_bpermute(addrA, (int)W[2 * kk][1]);
            u32 w1b = (u32)__builtin_amdgcn_ds_bpermute(addrA, (int)W[2 * kk + 1][1]);
            u32 w2a = (u32)__builtin_amdgcn_ds_bpermute(addrB, (int)W[2 * kk][0]);
            u32 w2b = (u32)__builtin_amdgcn_ds_bpermute(addrB, (int)W[2 * kk + 1][0]);
            u32 w3a = (u32)__builtin_amdgcn_ds_bpermute(addrB, (int)W[2 * kk][1]);
            u32 w3b = (u32)__builtin_amdgcn_ds_bpermute(addrB, (int)W[2 * kk + 1][1]);
            union { u32 w[4]; bf16x8 v; } bu;
            bu.w[0] = hiq ? w0b : w0a;
            bu.w[1] = hiq ? w1b : w1a;
            bu.w[2] = hiq ? w2b : w2a;
            bu.w[3] = hiq ? w3b : w3a;
            __builtin_amdgcn_s_setprio(1);
#pragma unroll
            for (int ni = 0; ni < 8; ni++) {
                bf16x8 av = *(const bf16x8*)&lVt[(ni * 16 + l16) * VSTR + kk * 32 + quad * 8];
                oc[ni] = __builtin_amdgcn_mfma_f32_16x16x32_bf16(av, bu.v, oc[ni], 0, 0, 0);
            }
            __builtin_amdgcn_s_setprio(0);
        }
    }

    // epilogue: O[t][d] = oc / l_i  (l_i per lane, col t = l16 -> no LDS broadcast)
    float invl = 1.f / l_i;
    size_t obase = ((size_t)(b * Tc + q0 + wave * 16 + l16) * Hc + h) * Kc;
#pragma unroll
    for (int ni = 0; ni < 8; ni++) {
        u16 r4[4];
#pragma unroll
        for (int r = 0; r < 4; r++) r4[r] = f2bf(oc[ni][r] * invl);
        *(uint2*)&Ob[obase + ni * 16 + quad * 4] = *(uint2*)r4;
    }
}

extern "C" void kernel_launch(void* const* d_in, const int* in_sizes, int n_in,
                              void* d_out, int out_size, void* d_ws, size_t ws_size,
                              hipStream_t stream) {
    const float* hidden  = (const float*)d_in[0];
    const float* wq      = (const float*)d_in[1];
    const float* wk      = (const float*)d_in[2];
    const float* wv      = (const float*)d_in[3];
    const float* wo      = (const float*)d_in[4];
    const float* q_scale = (const float*)d_in[5];
    const float* k_scale = (const float*)d_in[6];
    const int*   segids  = (const int*)d_in[7];
    float* out = (float*)d_out;

    char* ws = (char*)d_ws;
    size_t off = 0;
    auto alloc = [&](size_t bytes) -> void* {
        void* p = ws + off;
        off += (bytes + 255) & ~(size_t)255;
        return p;
    };
    u16* hbf  = (u16*)alloc((size_t)Bc * Tc * Dc * 2);        // hidden bf16
    u16* wqT  = (u16*)alloc((size_t)Hc * Kc * Dc * 2);        // (2048 x 2048) \  adjacent:
    u16* wkT  = (u16*)alloc((size_t)Gc * Kc * Dc * 2);        // (512 x 2048)   } one 3072-row B^T
    u16* wvT  = (u16*)alloc((size_t)Gc * Kc * Dc * 2);        // (512 x 2048)  /
    u16* woT  = (u16*)alloc((size_t)Dc * Hc * Kc * 2);        // (2048 x 2048)
    u16* qb   = (u16*)alloc((size_t)Bc * Tc * Hc * Kc * 2);
    u16* kb   = (u16*)alloc((size_t)Bc * Tc * Gc * Kc * 2);
    u16* vtb  = (u16*)alloc((size_t)Bc * Gc * Kc * Tc * 2);   // V^T [b][g][d][t]
    u16* attn = (u16*)alloc((size_t)Bc * Tc * Hc * Kc * 2);
    int* posb = (int*)alloc((size_t)Bc * Tc * 4);
    (void)ws_size; (void)in_sizes; (void)n_in; (void)out_size;

    const int M = Bc * Tc;   // 8192
    const float qsc = 0.08838834764831845f;   // K^-0.5 folded into q rms_rope

    cvt_f2bf<<<(Bc * Tc * Dc) / 1024, 256, 0, stream>>>(hidden, hbf, Bc * Tc * Dc);
    transpose_f2bf<<<dim3(64, 64), 256, 0, stream>>>(wq, wqT, Dc, Hc * Kc);
    transpose_f2bf<<<dim3(16, 64), 256, 0, stream>>>(wk, wkT, Dc, Gc * Kc);
    transpose_f2bf<<<dim3(16, 64), 256, 0, stream>>>(wv, wvT, Dc, Gc * Kc);
    transpose_f2bf<<<dim3(64, 64), 256, 0, stream>>>(wo, woT, Hc * Kc, Dc);
    pos_kernel<<<(Bc * Tc) / 256, 256, 0, stream>>>(segids, posb);

    // merged Q+K+V projection: N = 3072 over adjacent [wqT; wkT; wvT]
    gemm_qkv<<<dim3(3072 / GBN, M / GBM), 256, 0, stream>>>(hbf, wqT, qb, kb, vtb, M, Dc);

    rms_rope<<<(M * Hc) / 4, 256, 0, stream>>>(qb, q_scale, posb, Hc, qsc);
    rms_rope<<<(M * Gc) / 4, 256, 0, stream>>>(kb, k_scale, posb, Gc, 1.0f);

    flash_attn<<<dim3(Tc / 64, Hc, Bc), 256, 0, stream>>>(qb, kb, vtb, segids, posb, attn);

    gemm_bt<<<dim3(Dc / GBN, M / GBM), 256, 0, stream>>>(attn, woT, out, nullptr, M, Dc, Hc * Kc);
}

// Round 2
// 596.587 us; speedup vs baseline: 1.0729x; 1.0285x over previous
//
#include <hip/hip_runtime.h>

typedef unsigned short u16;
typedef unsigned int u32;
using f32x4 = __attribute__((ext_vector_type(4))) float;
using bf16x8 = __attribute__((ext_vector_type(8))) __bf16;

constexpr int Bc = 4, Tc = 2048, Dc = 2048, Hc = 16, Gc = 4, Kc = 128;
constexpr float EPSc = 1e-6f;

__device__ __forceinline__ u16 f2bf(float f) {
    u32 u = __float_as_uint(f);
    u = (u + 0x7fffu + ((u >> 16) & 1u)) >> 16;
    return (u16)u;
}
__device__ __forceinline__ float bf2f(u16 h) {
    return __uint_as_float(((u32)h) << 16);
}

// async global->LDS, 16B per lane; LDS dest must be wave-uniform base + lane*16
__device__ __forceinline__ void async_ld16(void* lds, const void* g) {
    __builtin_amdgcn_global_load_lds(
        (const __attribute__((address_space(1))) unsigned int*)g,
        (__attribute__((address_space(3))) unsigned int*)lds, 16, 0, 0);
}

// raw barrier: waits own LDS ops, does NOT drain vmcnt (prefetch stays in flight)
__device__ __forceinline__ void sync_lgkm() {
    asm volatile("s_waitcnt lgkmcnt(0)" ::: "memory");
    __builtin_amdgcn_s_barrier();
    asm volatile("" ::: "memory");
}

__device__ __forceinline__ u32 cvt_pk_bf16(float lo, float hi) {
    u32 r;
    asm("v_cvt_pk_bf16_f32 %0, %1, %2" : "=v"(r) : "v"(lo), "v"(hi));
    return r;
}

// ---------------- fp32 -> bf16 convert ----------------
__global__ __launch_bounds__(256) void cvt_f2bf(const float* __restrict__ in,
                                                u16* __restrict__ out, int n) {
    int i = (blockIdx.x * 256 + threadIdx.x) * 4;
    if (i >= n) return;
    float4 f = *(const float4*)(in + i);
    u16 r[4] = { f2bf(f.x), f2bf(f.y), f2bf(f.z), f2bf(f.w) };
    *(uint2*)(out + i) = *(uint2*)r;
}

// ------- transpose+convert: in (rows x cols) f32 -> out (cols x rows) bf16 -------
__global__ __launch_bounds__(256) void transpose_f2bf(const float* __restrict__ in,
                                                      u16* __restrict__ out,
                                                      int rows, int cols) {
    __shared__ float tile[32][33];
    int tx = threadIdx.x & 31, ty = threadIdx.x >> 5;
    int c0 = blockIdx.x * 32, r0 = blockIdx.y * 32;
#pragma unroll
    for (int j = 0; j < 4; j++)
        tile[ty + j * 8][tx] = in[(size_t)(r0 + ty + j * 8) * cols + c0 + tx];
    __syncthreads();
#pragma unroll
    for (int j = 0; j < 4; j++)
        out[(size_t)(c0 + ty + j * 8) * rows + r0 + tx] = f2bf(tile[tx][ty + j * 8]);
}

// ---------------- positions from (sorted) segment ids ----------------
__global__ void pos_kernel(const int* __restrict__ seg, int* __restrict__ pos) {
    int idx = blockIdx.x * 256 + threadIdx.x;
    if (idx >= Bc * Tc) return;
    int b = idx / Tc, t = idx - b * Tc;
    const int* s = seg + b * Tc;
    int v = s[t];
    int lo = 0, hi = t;
    while (lo < hi) { int mid = (lo + hi) >> 1; if (s[mid] < v) lo = mid + 1; else hi = mid; }
    pos[idx] = t - lo;   // t - seg_start
}

// ---------------- bf16 GEMM (m97 structure): C(MxN) = A(MxKd) * Bt(NxKd)^T ----------------
#define GBM 128
#define GBN 128
#define GBK 32

__global__ __launch_bounds__(256) void gemm_bt(const u16* __restrict__ A,
                                               const u16* __restrict__ Bt,
                                               float* __restrict__ Cf, u16* __restrict__ Cb,
                                               int M, int N, int Kd) {
    __shared__ __align__(16) u16 lA[GBM * GBK];   // unpadded: required by global_load_lds lane order
    __shared__ __align__(16) u16 lB[GBN * GBK];
    const int tid = threadIdx.x;
    const int m0 = blockIdx.y * GBM, n0 = blockIdx.x * GBN;
    const int wave = tid >> 6, lane = tid & 63;
    const int l16 = lane & 15, quad = lane >> 4;
    const int wm = (wave & 1) * 64, wn = (wave >> 1) * 64;

    const int c0 = tid, c1 = tid + 256;
    const u16* gA0 = A + (size_t)(m0 + (c0 >> 2)) * Kd + (c0 & 3) * 8;
    const u16* gA1 = A + (size_t)(m0 + (c1 >> 2)) * Kd + (c1 & 3) * 8;
    const u16* gB0 = Bt + (size_t)(n0 + (c0 >> 2)) * Kd + (c0 & 3) * 8;
    const u16* gB1 = Bt + (size_t)(n0 + (c1 >> 2)) * Kd + (c1 & 3) * 8;
    u16* sA0 = &lA[c0 * 8];
    u16* sA1 = &lA[c1 * 8];
    u16* sB0 = &lB[c0 * 8];
    u16* sB1 = &lB[c1 * 8];

    const f32x4 fz = {0.f, 0.f, 0.f, 0.f};
    f32x4 acc[4][4];
#pragma unroll
    for (int i = 0; i < 4; i++)
#pragma unroll
        for (int j = 0; j < 4; j++) acc[i][j] = fz;

    for (int k0 = 0; k0 < Kd; k0 += GBK) {
        __syncthreads();
        async_ld16(sA0, gA0 + k0);
        async_ld16(sA1, gA1 + k0);
        async_ld16(sB0, gB0 + k0);
        async_ld16(sB1, gB1 + k0);
        __syncthreads();
        bf16x8 af[4], bg[4];
#pragma unroll
        for (int i = 0; i < 4; i++) {
            af[i] = *(const bf16x8*)&lA[(wm + i * 16 + l16) * GBK + quad * 8];
            bg[i] = *(const bf16x8*)&lB[(wn + i * 16 + l16) * GBK + quad * 8];
        }
#pragma unroll
        for (int mi = 0; mi < 4; mi++)
#pragma unroll
            for (int ni = 0; ni < 4; ni++)
                acc[mi][ni] = __builtin_amdgcn_mfma_f32_16x16x32_bf16(af[mi], bg[ni], acc[mi][ni], 0, 0, 0);
    }

#pragma unroll
    for (int mi = 0; mi < 4; mi++)
#pragma unroll
        for (int ni = 0; ni < 4; ni++)
#pragma unroll
            for (int r = 0; r < 4; r++) {
                int row = m0 + wm + mi * 16 + quad * 4 + r;   // C/D: row=quad*4+reg
                int col = n0 + wn + ni * 16 + l16;            //      col=lane&15
                float v = acc[mi][ni][r];
                if (Cf) Cf[(size_t)row * N + col] = v;
                else    Cb[(size_t)row * N + col] = f2bf(v);
            }
}

// ------- merged QKV GEMM: N=3072 over [wqT;wkT;wvT]; Q->qb, K->kb, V->Vt[b][g][d][t] -------
__global__ __launch_bounds__(256) void gemm_qkv(const u16* __restrict__ A,
                                                const u16* __restrict__ Bt,
                                                u16* __restrict__ qb, u16* __restrict__ kb,
                                                u16* __restrict__ vtb, int M, int Kd) {
    __shared__ __align__(16) u16 lA[GBM * GBK];
    __shared__ __align__(16) u16 lB[GBN * GBK];
    const int tid = threadIdx.x;
    const int m0 = blockIdx.y * GBM, n0 = blockIdx.x * GBN;
    const int wave = tid >> 6, lane = tid & 63;
    const int l16 = lane & 15, quad = lane >> 4;
    const int wm = (wave & 1) * 64, wn = (wave >> 1) * 64;

    const int c0 = tid, c1 = tid + 256;
    const u16* gA0 = A + (size_t)(m0 + (c0 >> 2)) * Kd + (c0 & 3) * 8;
    const u16* gA1 = A + (size_t)(m0 + (c1 >> 2)) * Kd + (c1 & 3) * 8;
    const u16* gB0 = Bt + (size_t)(n0 + (c0 >> 2)) * Kd + (c0 & 3) * 8;
    const u16* gB1 = Bt + (size_t)(n0 + (c1 >> 2)) * Kd + (c1 & 3) * 8;
    u16* sA0 = &lA[c0 * 8];
    u16* sA1 = &lA[c1 * 8];
    u16* sB0 = &lB[c0 * 8];
    u16* sB1 = &lB[c1 * 8];

    const f32x4 fz = {0.f, 0.f, 0.f, 0.f};
    f32x4 acc[4][4];
#pragma unroll
    for (int i = 0; i < 4; i++)
#pragma unroll
        for (int j = 0; j < 4; j++) acc[i][j] = fz;

    for (int k0 = 0; k0 < Kd; k0 += GBK) {
        __syncthreads();
        async_ld16(sA0, gA0 + k0);
        async_ld16(sA1, gA1 + k0);
        async_ld16(sB0, gB0 + k0);
        async_ld16(sB1, gB1 + k0);
        __syncthreads();
        bf16x8 af[4], bg[4];
#pragma unroll
        for (int i = 0; i < 4; i++) {
            af[i] = *(const bf16x8*)&lA[(wm + i * 16 + l16) * GBK + quad * 8];
            bg[i] = *(const bf16x8*)&lB[(wn + i * 16 + l16) * GBK + quad * 8];
        }
#pragma unroll
        for (int mi = 0; mi < 4; mi++)
#pragma unroll
            for (int ni = 0; ni < 4; ni++)
                acc[mi][ni] = __builtin_amdgcn_mfma_f32_16x16x32_bf16(af[mi], bg[ni], acc[mi][ni], 0, 0, 0);
    }

    const int nbase = n0 + wn;   // 64-aligned; regions split at 2048 / 2560 (both 64-aligned)
    if (nbase < 2048) {
        // Q: qb[(b,t)][(h,d)] = [M][2048]
#pragma unroll
        for (int mi = 0; mi < 4; mi++)
#pragma unroll
            for (int ni = 0; ni < 4; ni++)
#pragma unroll
                for (int r = 0; r < 4; r++) {
                    int row = m0 + wm + mi * 16 + quad * 4 + r;
                    int col = nbase + ni * 16 + l16;
                    qb[(size_t)row * 2048 + col] = f2bf(acc[mi][ni][r]);
                }
    } else if (nbase < 2560) {
        // K: kb[(b,t)][(g,d)] = [M][512]
#pragma unroll
        for (int mi = 0; mi < 4; mi++)
#pragma unroll
            for (int ni = 0; ni < 4; ni++)
#pragma unroll
                for (int r = 0; r < 4; r++) {
                    int row = m0 + wm + mi * 16 + quad * 4 + r;
                    int col = nbase + ni * 16 + l16 - 2048;
                    kb[(size_t)row * 512 + col] = f2bf(acc[mi][ni][r]);
                }
    } else {
        // V: transposed Vt[b][g][d][t]; 4 consecutive t per lane -> 8B store
#pragma unroll
        for (int mi = 0; mi < 4; mi++)
#pragma unroll
            for (int ni = 0; ni < 4; ni++) {
                int nv = nbase + ni * 16 + l16 - 2560;
                int g = nv >> 7, d = nv & 127;
                int m = m0 + wm + mi * 16 + quad * 4;
                int b = m >> 11, t = m & 2047;
                u16 r4[4];
#pragma unroll
                for (int r = 0; r < 4; r++) r4[r] = f2bf(acc[mi][ni][r]);
                *(uint2*)&vtb[(((size_t)b * Gc + g) * Kc + d) * Tc + t] = *(uint2*)r4;
            }
    }
}

// ---------------- fused RMSNorm + RoPE (+ optional smul fold), in place ----------------
__global__ __launch_bounds__(256) void rms_rope(u16* __restrict__ X,
                                                const float* __restrict__ sc,
                                                const int* __restrict__ pos, int NH,
                                                float smul) {
    int row = blockIdx.x * 4 + (threadIdx.x >> 6);   // one wave per (b,t,head) row
    int lane = threadIdx.x & 63;
    int bt = row / NH;
    u16* xp = X + (size_t)row * Kc;
    float x1 = bf2f(xp[lane]), x2 = bf2f(xp[lane + 64]);   // rope pairs (j, j+64)
    float ss = x1 * x1 + x2 * x2;
#pragma unroll
    for (int m = 1; m < 64; m <<= 1) ss += __shfl_xor(ss, m, 64);
    float rn = rsqrtf(ss * (1.f / 128.f) + EPSc) * smul;   // fold attn scale into q
    float y1 = x1 * rn * sc[lane];
    float y2 = x2 * rn * sc[lane + 64];
    float inv_freq = expf(-logf(10000.f) * ((float)(2 * lane) * (1.f / 128.f)));
    float ang = (float)pos[bt] * inv_freq;
    float sv, cv;
    sincosf(ang, &sv, &cv);
    xp[lane]      = f2bf(y1 * cv - y2 * sv);
    xp[lane + 64] = f2bf(y2 * cv + y1 * sv);
}

// ---------------- flash attention: swapped-QK^T, in-register softmax ----------------
// S^T = mfma(K_frag, Q_frag): lane's col t = l16 -> m/l/alpha are per-lane scalars.
// P^T B-fragment for PV built via cvt_pk_bf16 + 16x ds_bpermute (no lP LDS round trip).
// Raw s_barrier (no vmcnt drain): next-tile prefetch loads stay in flight across
// the barrier and drain at the next iteration's ds_write (full compute overlap).
// XCD swizzle: blocks grouped by (b,g) so 4 heads sharing K/V land on one XCD's L2.
// Epilogue: O^T -> O transpose through LDS (reuse lK) for coalesced 16B/lane stores.
#define KSTR 136   // 128+8: stride 68 dwords == 4 mod 32 -> conflict-minimal frag reads
#define VSTR 72    // 64+8:  stride 36 dwords == 4 mod 32

__global__ __launch_bounds__(256, 4) void flash_attn(const u16* __restrict__ Qb,
                                                     const u16* __restrict__ Kb,
                                                     const u16* __restrict__ Vt,
                                                     const int* __restrict__ seg,
                                                     const int* __restrict__ pos,
                                                     u16* __restrict__ Ob) {
    __shared__ __align__(16) u16 lK[64 * KSTR];
    __shared__ __align__(16) u16 lVt[128 * VSTR];   // V transposed: [d][s]
    __shared__ int lSeg[64];                        // seg id per s of current tile

    // XCD-aware decode: 2048 blocks = 8 xcd x (2 bg x 4 h x 32 q); xcd = lin % 8.
    // All 4 heads of a (b,g) (1MB K + 1MB V) stay on one XCD -> L2-resident.
    const int lin = (int)blockIdx.x + 32 * ((int)blockIdx.y + 16 * (int)blockIdx.z);
    const int xcd = lin & 7, slot = lin >> 3;        // slot in [0,256)
    const int bg = xcd + 8 * (slot >> 7);            // [0,16)
    const int sub = slot & 127;
    const int b = bg >> 2, g = bg & 3;
    const int h = g * 4 + (sub >> 5);
    const int q0 = (31 - (sub & 31)) * 64;           // heavy tiles first
    const int tid = threadIdx.x;
    const int wave = tid >> 6, lane = tid & 63;
    const int l16 = lane & 15, quad = lane >> 4;

    // Q fragments in registers (already scaled by K^-0.5 in rms_rope).
    // Used as the B-operand of the swapped QK^T (same per-lane layout as A).
    bf16x8 qf[4];
#pragma unroll
    for (int kk = 0; kk < 4; kk++)
        qf[kk] = *(const bf16x8*)&Qb[((size_t)(b * Tc + q0 + wave * 16 + l16) * Hc + h) * Kc + kk * 32 + quad * 8];

    const int tg1 = q0 + wave * 16 + l16;          // this lane's q row (t)
    const int sgt1 = seg[b * Tc + tg1];
    const bool segQuni = (seg[b * Tc + q0] == seg[b * Tc + q0 + 63]);

    float m_i = -1e30f, l_i = 0.f;                 // per-lane scalars (t = l16 col)
    const f32x4 fz = {0.f, 0.f, 0.f, 0.f};
    f32x4 oc[8];   // O^T C-tiles: row d = ni*16+quad*4+r, col t = wave*16+l16
#pragma unroll
    for (int i = 0; i < 8; i++) oc[i] = fz;

    const int seg_start_exact = q0 - pos[b * Tc + q0];   // first index of q0's segment
    const int s_begin = (seg_start_exact >> 6) << 6;     // tile-aligned (may include prev segment!)

    // bpermute source addrs for the P^T quad-redistribution:
    //   word m' of bp at lane (l16,q) <- W[2kk+(q>>1)][m'&1] from lane l16+16*((q&1)*2+(m'>>1))
    const int addrA = (l16 + ((quad & 1) << 5)) << 2;   // m' = 0,1
    const int addrB = addrA + 64;                       // m' = 2,3
    const bool hiq = quad >= 2;

    // prefetch first K/V tile + seg row into registers
    uint4 kpre[4], vpre[4];
#pragma unroll
    for (int it = 0; it < 4; it++) {
        int c = tid + it * 256;
        kpre[it] = *(const uint4*)&Kb[((size_t)(b * Tc + s_begin + (c >> 4)) * Gc + g) * Kc + (c & 15) * 8];
        vpre[it] = *(const uint4*)&Vt[(((size_t)b * Gc + g) * Kc + (c >> 3)) * Tc + s_begin + (c & 7) * 8];
    }
    int segpre = (tid < 64) ? seg[b * Tc + s_begin + tid] : 0;

    for (int s0 = s_begin; s0 <= q0; s0 += 64) {
        sync_lgkm();   // all waves' LDS reads of prior tile done (no vmcnt drain)
        // stage K tile (64 x 128) and Vt tile (128 x 64) from prefetch regs
        // (compiler waits vmcnt for kpre/vpre deps here -> latency was hidden under compute)
#pragma unroll
        for (int it = 0; it < 4; it++) {
            int c = tid + it * 256;
            *(uint4*)&lK[(c >> 4) * KSTR + (c & 15) * 8] = kpre[it];
        }
#pragma unroll
        for (int it = 0; it < 4; it++) {
            int c = tid + it * 256;
            *(uint4*)&lVt[(c >> 3) * VSTR + (c & 7) * 8] = vpre[it];
        }
        if (tid < 64) lSeg[tid] = segpre;
        // prefetch next tile: stays in flight across the barrier below
        if (s0 + 64 <= q0) {
#pragma unroll
            for (int it = 0; it < 4; it++) {
                int c = tid + it * 256;
                kpre[it] = *(const uint4*)&Kb[((size_t)(b * Tc + s0 + 64 + (c >> 4)) * Gc + g) * Kc + (c & 15) * 8];
                vpre[it] = *(const uint4*)&Vt[(((size_t)b * Gc + g) * Kc + (c >> 3)) * Tc + s0 + 64 + (c & 7) * 8];
            }
            if (tid < 64) segpre = seg[b * Tc + s0 + 64 + tid];
        }
        sync_lgkm();   // staging visible; vmem prefetch NOT drained

        // S^T = K Q^T : row s = mi*16+quad*4+r, col t = l16
        f32x4 sacc[4];
#pragma unroll
        for (int mi = 0; mi < 4; mi++) sacc[mi] = fz;
        __builtin_amdgcn_s_setprio(1);
#pragma unroll
        for (int kk = 0; kk < 4; kk++) {
#pragma unroll
            for (int mi = 0; mi < 4; mi++) {
                bf16x8 bk = *(const bf16x8*)&lK[(mi * 16 + l16) * KSTR + kk * 32 + quad * 8];
                sacc[mi] = __builtin_amdgcn_mfma_f32_16x16x32_bf16(bk, qf[kk], sacc[mi], 0, 0, 0);
            }
        }
        __builtin_amdgcn_s_setprio(0);

        // mask + row max (row = fixed t per lane; s spans regs + quads)
        const bool fast = segQuni && (s0 >= seg_start_exact) && (s0 + 64 <= q0);
        float rmax = -1e30f;
        if (fast) {
#pragma unroll
            for (int mi = 0; mi < 4; mi++)
#pragma unroll
                for (int r = 0; r < 4; r++) rmax = fmaxf(rmax, sacc[mi][r]);
        } else {
#pragma unroll
            for (int mi = 0; mi < 4; mi++) {
                int sl = mi * 16 + quad * 4;
#pragma unroll
                for (int r = 0; r < 4; r++) {
                    bool ok = (s0 + sl + r <= tg1) && (lSeg[sl + r] == sgt1);
                    float x = ok ? sacc[mi][r] : -1e30f;
                    sacc[mi][r] = x;
                    rmax = fmaxf(rmax, x);
                }
            }
        }
        rmax = fmaxf(rmax, __shfl_xor(rmax, 16, 64));
        rmax = fmaxf(rmax, __shfl_xor(rmax, 32, 64));

        float mnew = fmaxf(m_i, rmax);
        float alpha = __expf(m_i - mnew);
        m_i = mnew;

        // P = exp(S - m); pack to bf16 pairs in-register
        float psum = 0.f;
        u32 W[4][2];
#pragma unroll
        for (int mi = 0; mi < 4; mi++) {
            float p[4];
#pragma unroll
            for (int r = 0; r < 4; r++) {
                float x = sacc[mi][r];
                p[r] = (x > -1e29f) ? __expf(x - m_i) : 0.f;
                psum += p[r];
            }
            W[mi][0] = cvt_pk_bf16(p[0], p[1]);
            W[mi][1] = cvt_pk_bf16(p[2], p[3]);
        }
        psum += __shfl_xor(psum, 16, 64);
        psum += __shfl_xor(psum, 32, 64);
        l_i = l_i * alpha + psum;

        // rescale O^T (col t = l16 matches per-lane alpha)
#pragma unroll
        for (int ni = 0; ni < 8; ni++)
#pragma unroll
            for (int r = 0; r < 4; r++) oc[ni][r] *= alpha;

        // O^T += V^T P^T ; P^T B-frag built via quad redistribution (16 bpermute)
#pragma unroll
        for (int kk = 0; kk < 2; kk++) {
            u32 w0a = (u32)__builtin_amdgcn_ds_bpermute(addrA, (int)W[2 * kk][0]);
            u32 w0b = (u32)__builtin_amdgcn_ds_bpermute(addrA, (int)W[2 * kk + 1][0]);
            u32 w1a = (u32)__builtin_amdgcn_ds_bpermute(addrA, (int)W[2 * kk][1]);
            u32 w1b = (u32)__builtin_amdgcn_ds_bpermute(addrA, (int)W[2 * kk + 1][1]);
            u32 w2a = (u32)__builtin_amdgcn_ds_bpermute(addrB, (int)W[2 * kk][0]);
            u32 w2b = (u32)__builtin_amdgcn_ds_bpermute(addrB, (int)W[2 * kk + 1][0]);
            u32 w3a = (u32)__builtin_amdgcn_ds_bpermute(addrB, (int)W[2 * kk][1]);
            u32 w3b = (u32)__builtin_amdgcn_ds_bpermute(addrB, (int)W[2 * kk + 1][1]);
            union { u32 w[4]; bf16x8 v; } bu;
            bu.w[0] = hiq ? w0b : w0a;
            bu.w[1] = hiq ? w1b : w1a;
            bu.w[2] = hiq ? w2b : w2a;
            bu.w[3] = hiq ? w3b : w3a;
            __builtin_amdgcn_s_setprio(1);
#pragma unroll
            for (int ni = 0; ni < 8; ni++) {
                bf16x8 av = *(const bf16x8*)&lVt[(ni * 16 + l16) * VSTR + kk * 32 + quad * 8];
                oc[ni] = __builtin_amdgcn_mfma_f32_16x16x32_bf16(av, bu.v, oc[ni], 0, 0, 0);
            }
            __builtin_amdgcn_s_setprio(0);
        }
    }

    // ---- epilogue: O^T -> O transpose via LDS (reuse lK), coalesced stores ----
    __syncthreads();                 // all waves done with lK/lVt MFMA reads
    u16* lO = lK;                    // [64][KSTR] scratch, row = t-local, col = d
    float invl = 1.f / l_i;
    const int tloc = wave * 16 + l16;
#pragma unroll
    for (int ni = 0; ni < 8; ni++) {
        u16 r4[4];
#pragma unroll
        for (int r = 0; r < 4; r++) r4[r] = f2bf(oc[ni][r] * invl);
        *(uint2*)&lO[tloc * KSTR + ni * 16 + quad * 4] = *(uint2*)r4;
    }
    __syncthreads();
    // each wave stores its own 16 t-rows: 16 lanes x 16B = 256B contiguous per row
#pragma unroll
    for (int j = 0; j < 4; j++) {
        int t2 = wave * 16 + j * 4 + quad;
        uint4 vv = *(const uint4*)&lO[t2 * KSTR + l16 * 8];
        *(uint4*)&Ob[((size_t)(b * Tc + q0 + t2) * Hc + h) * Kc + l16 * 8] = vv;
    }
}

extern "C" void kernel_launch(void* const* d_in, const int* in_sizes, int n_in,
                              void* d_out, int out_size, void* d_ws, size_t ws_size,
                              hipStream_t stream) {
    const float* hidden  = (const float*)d_in[0];
    const float* wq      = (const float*)d_in[1];
    const float* wk      = (const float*)d_in[2];
    const float* wv      = (const float*)d_in[3];
    const float* wo      = (const float*)d_in[4];
    const float* q_scale = (const float*)d_in[5];
    const float* k_scale = (const float*)d_in[6];
    const int*   segids  = (const int*)d_in[7];
    float* out = (float*)d_out;

    char* ws = (char*)d_ws;
    size_t off = 0;
    auto alloc = [&](size_t bytes) -> void* {
        void* p = ws + off;
        off += (bytes + 255) & ~(size_t)255;
        return p;
    };
    u16* hbf  = (u16*)alloc((size_t)Bc * Tc * Dc * 2);        // hidden bf16
    u16* wqT  = (u16*)alloc((size_t)Hc * Kc * Dc * 2);        // (2048 x 2048) \  adjacent:
    u16* wkT  = (u16*)alloc((size_t)Gc * Kc * Dc * 2);        // (512 x 2048)   } one 3072-row B^T
    u16* wvT  = (u16*)alloc((size_t)Gc * Kc * Dc * 2);        // (512 x 2048)  /
    u16* woT  = (u16*)alloc((size_t)Dc * Hc * Kc * 2);        // (2048 x 2048)
    u16* qb   = (u16*)alloc((size_t)Bc * Tc * Hc * Kc * 2);
    u16* kb   = (u16*)alloc((size_t)Bc * Tc * Gc * Kc * 2);
    u16* vtb  = (u16*)alloc((size_t)Bc * Gc * Kc * Tc * 2);   // V^T [b][g][d][t]
    u16* attn = (u16*)alloc((size_t)Bc * Tc * Hc * Kc * 2);
    int* posb = (int*)alloc((size_t)Bc * Tc * 4);
    (void)ws_size; (void)in_sizes; (void)n_in; (void)out_size;

    const int M = Bc * Tc;   // 8192
    const float qsc = 0.08838834764831845f;   // K^-0.5 folded into q rms_rope

    cvt_f2bf<<<(Bc * Tc * Dc) / 1024, 256, 0, stream>>>(hidden, hbf, Bc * Tc * Dc);
    transpose_f2bf<<<dim3(64, 64), 256, 0, stream>>>(wq, wqT, Dc, Hc * Kc);
    transpose_f2bf<<<dim3(16, 64), 256, 0, stream>>>(wk, wkT, Dc, Gc * Kc);
    transpose_f2bf<<<dim3(16, 64), 256, 0, stream>>>(wv, wvT, Dc, Gc * Kc);
    transpose_f2bf<<<dim3(64, 64), 256, 0, stream>>>(wo, woT, Hc * Kc, Dc);
    pos_kernel<<<(Bc * Tc) / 256, 256, 0, stream>>>(segids, posb);

    // merged Q+K+V projection: N = 3072 over adjacent [wqT; wkT; wvT]
    gemm_qkv<<<dim3(3072 / GBN, M / GBM), 256, 0, stream>>>(hbf, wqT, qb, kb, vtb, M, Dc);

    rms_rope<<<(M * Hc) / 4, 256, 0, stream>>>(qb, q_scale, posb, Hc, qsc);
    rms_rope<<<(M * Gc) / 4, 256, 0, stream>>>(kb, k_scale, posb, Gc, 1.0f);

    flash_attn<<<dim3(Tc / 64, Hc, Bc), 256, 0, stream>>>(qb, kb, vtb, segids, posb, attn);

    gemm_bt<<<dim3(Dc / GBN, M / GBM), 256, 0, stream>>>(attn, woT, out, nullptr, M, Dc, Hc * Kc);
}